// Round 14
// baseline (551.018 us; speedup 1.0000x reference)
//
#include <hip/hip_runtime.h>
#include <hip/hip_bf16.h>
#include <hip/hip_cooperative_groups.h>

namespace cg = cooperative_groups;

typedef __hip_bfloat16 bf16;
typedef __attribute__((ext_vector_type(8))) short short8;   // 8 bf16 = 4 VGPRs
typedef __attribute__((ext_vector_type(4))) short short4v;  // 4 bf16 = 2 VGPRs
typedef __attribute__((ext_vector_type(4))) float f32x4;    // MFMA C/D

#define BB 4
#define NN 2048
#define DD 256
#define HH 8
#define HD 32
#define BN (BB*NN)          // 8192
#define ELEMS (BN*DD)       // 2097152

// ---------------------------------------------------------------------------
// Scratch in module .bss (~33 MB).
// ---------------------------------------------------------------------------
__device__ __attribute__((aligned(256))) unsigned short g_xb [ELEMS]; // x as bf16 [n][k]
__device__ __attribute__((aligned(256))) unsigned short g_qb [ELEMS]; // [bh][n][d] bf16 (pre-scaled)
__device__ __attribute__((aligned(256))) unsigned short g_kb [ELEMS]; // [bh][n][d] bf16
__device__ __attribute__((aligned(256))) unsigned short g_tA [ELEMS]; // [bh][d][n] bf16
__device__ __attribute__((aligned(256))) unsigned short g_tB [ELEMS]; // [bh][d][n] bf16
__device__ __attribute__((aligned(256))) float          g_acc[ELEMS]; // [b][n][D] f32 (c0*V)
__device__ __attribute__((aligned(256))) unsigned short g_mg [ELEMS]; // merged bf16 [n][D]
__device__ __attribute__((aligned(256))) unsigned short g_wt [4*DD*DD]; // W^T bf16 [mat][n][k]
__device__ __attribute__((aligned(256))) float g_bias[4*DD];
__device__ __attribute__((aligned(256))) float g_cf[HH*4];
__device__ __attribute__((aligned(256))) float g_invl[BB*HH*NN];      // fallback path only

__device__ __forceinline__ float b2f(unsigned short u) {
    union { unsigned int i; float f; } c; c.i = ((unsigned int)u) << 16; return c.f;
}
__device__ __forceinline__ unsigned short f2b(float f) {           // safe path
    bf16 h = __float2bfloat16(f);
    return *reinterpret_cast<unsigned short*>(&h);
}
// pack two f32 -> one u32 of two bf16 (RNE).  gfx950 has a 1-instr pk cvt.
#if __has_builtin(__builtin_amdgcn_cvt_pk_bf16_f32)
typedef __attribute__((ext_vector_type(2))) __bf16 bf16x2t;
__device__ __forceinline__ unsigned int pk2(float a, float b) {
    union { bf16x2t v; unsigned int u; } c;
    c.v = __builtin_amdgcn_cvt_pk_bf16_f32(a, b);
    return c.u;
}
#else
__device__ __forceinline__ unsigned int pk2(float a, float b) {
    unsigned int ua = __float_as_uint(a), ub = __float_as_uint(b);
    ua = (ua + 0x7FFFu + ((ua >> 16) & 1u)) >> 16;
    ub = (ub + 0x7FFFu + ((ub >> 16) & 1u)) & 0xFFFF0000u;
    return ua | ub;
}
#endif
__device__ __forceinline__ float ldin(const void* p, int i, int f32m) {
    return f32m ? ((const float*)p)[i] : b2f(((const unsigned short*)p)[i]);
}

// ---------------------------------------------------------------------------
// Async global->LDS (16B/lane), linear LDS layouts only (verified r24).
// ---------------------------------------------------------------------------
#if __has_builtin(__builtin_amdgcn_global_load_lds)
#define HAS_GLL 1
typedef const __attribute__((address_space(1))) unsigned int* gas_t;
typedef __attribute__((address_space(3))) unsigned int* las_t;
__device__ __forceinline__ void gll16(const void* gsrc, void* ldst) {
    __builtin_amdgcn_global_load_lds((gas_t)gsrc, (las_t)ldst, 16, 0, 0);
}
#else
#define HAS_GLL 0
#endif

// ---------------------------------------------------------------------------
// Per-block dtype probe (verified r23).
// ---------------------------------------------------------------------------
__device__ __forceinline__ int block_probe(const void* x, int tid, int nthr)
{
    __shared__ int cnt;
    if (tid == 0) cnt = 0;
    __syncthreads();
    const unsigned short* u = (const unsigned short*)x;
    int w = 0;
    for (int i = tid; i < 1024; i += nthr) {
        const int e = (u[2 * i] >> 7) & 0xFF;
        if (e < 100 || e > 140) ++w;
    }
    if (w) atomicAdd(&cnt, w);
    __syncthreads();
    return cnt > 300;
}

// ---------------------------------------------------------------------------
// Kernel A (r23, kept): merged prep.
// ---------------------------------------------------------------------------
__global__ __launch_bounds__(256) void prep_kernel(
    const void* __restrict__ x,
    const void* W0, const void* W1, const void* W2, const void* W3,
    const void* bq, const void* bk, const void* bv, const void* bo,
    const void* coeffs)
{
    const int t = threadIdx.x;
    const int f32m = block_probe(x, t, 256);

    if (blockIdx.x < 1024) {
        const size_t i0 = ((size_t)blockIdx.x * 256 + t) * 8;
        if (f32m) {
            const float4 a = *(const float4*)((const float*)x + i0);
            const float4 b = *(const float4*)((const float*)x + i0 + 4);
            union { uint4 v; unsigned int u[4]; } o;
            o.u[0] = pk2(a.x, a.y); o.u[1] = pk2(a.z, a.w);
            o.u[2] = pk2(b.x, b.y); o.u[3] = pk2(b.z, b.w);
            *(uint4*)(g_xb + i0) = o.v;
        } else {
            *(uint4*)(g_xb + i0) = *(const uint4*)((const unsigned short*)x + i0);
        }
        return;
    }

    __shared__ unsigned short tile[64][65];
    const int bi  = blockIdx.x - 1024;         // 0..63
    const int mat = bi >> 4;
    const int bx  = bi & 15;
    const void* W = (mat == 0) ? W0 : (mat == 1) ? W1 : (mat == 2) ? W2 : W3;
    const int k0 = (bx >> 2) * 64;
    const int n0 = (bx & 3) * 64;

    if (bi == 0) {
        g_bias[0 * DD + t] = ldin(bq, t, f32m);
        g_bias[1 * DD + t] = ldin(bk, t, f32m);
        g_bias[2 * DD + t] = ldin(bv, t, f32m);
        g_bias[3 * DD + t] = ldin(bo, t, f32m);
        if (t < 32) g_cf[t] = ldin(coeffs, t, f32m);
    }

    #pragma unroll
    for (int it = 0; it < 16; ++it) {
        const int flat = it * 256 + t;
        const int i = flat >> 6, j = flat & 63;
        tile[j][i] = f2b(ldin(W, (k0 + i) * DD + n0 + j, f32m));
    }
    __syncthreads();
    unsigned short* wt = g_wt + mat * DD * DD;
    #pragma unroll
    for (int it = 0; it < 16; ++it) {
        const int flat = it * 256 + t;
        const int nl = flat >> 6, kl = flat & 63;
        wt[(n0 + nl) * DD + k0 + kl] = tile[nl][kl];
    }
}

// ---------------------------------------------------------------------------
// Kernel 1 (r24, kept): QKV projection GEMM, 128x64 tile, gll staging.
// ---------------------------------------------------------------------------
__global__ __launch_bounds__(256) void qkv_gemm_kernel()
{
    __shared__ unsigned short xs[128 * 32];   // A tile 8 KB (linear)
    __shared__ unsigned short wl[64 * 32];    // B tile 4 KB (linear)
    const int t  = threadIdx.x;
    const int w  = t >> 6, l = t & 63, lg = l >> 4, ln = l & 15;
    const int wm = w >> 1, wn = w & 1;        // wave -> (M-half, N-half)
    const int r0 = blockIdx.x * 128;
    const int n0 = blockIdx.y * 64;
    const int mat = blockIdx.z;
    const unsigned short* wt = g_wt + mat * DD * DD;

    f32x4 acc[4][2];
    #pragma unroll
    for (int m = 0; m < 4; ++m)
        #pragma unroll
        for (int s = 0; s < 2; ++s) acc[m][s] = (f32x4){0,0,0,0};

    for (int kc = 0; kc < DD; kc += 32) {
        __syncthreads();
#if HAS_GLL
        #pragma unroll
        for (int c = 0; c < 2; ++c) {
            const int s = c * 256 + t;
            gll16(g_xb + (size_t)(r0 + (s >> 2)) * DD + kc + (s & 3) * 8,
                  xs + (s >> 2) * 32 + (s & 3) * 8);
        }
        gll16(wt + (size_t)(n0 + (t >> 2)) * DD + kc + (t & 3) * 8,
              wl + (t >> 2) * 32 + (t & 3) * 8);
#else
        #pragma unroll
        for (int c = 0; c < 2; ++c) {
            const int s = c * 256 + t;
            *(uint4*)(xs + (s >> 2) * 32 + (s & 3) * 8) =
                *(const uint4*)(g_xb + (size_t)(r0 + (s >> 2)) * DD + kc + (s & 3) * 8);
        }
        *(uint4*)(wl + (t >> 2) * 32 + (t & 3) * 8) =
            *(const uint4*)(wt + (size_t)(n0 + (t >> 2)) * DD + kc + (t & 3) * 8);
#endif
        __syncthreads();

        short8 af[4];
        #pragma unroll
        for (int m = 0; m < 4; ++m)
            af[m] = *(const short8*)(xs + (wm * 64 + m * 16 + ln) * 32 + lg * 8);
        #pragma unroll
        for (int s = 0; s < 2; ++s) {
            const short8 bfr = *(const short8*)(wl + (wn * 32 + s * 16 + ln) * 32 + lg * 8);
            #pragma unroll
            for (int m = 0; m < 4; ++m)
                acc[m][s] = __builtin_amdgcn_mfma_f32_16x16x32_bf16(af[m], bfr, acc[m][s], 0, 0, 0);
        }
    }

    const float QS = 0.17677669529663687f * 1.4426950408889634f; // scale*log2e
    #pragma unroll
    for (int s = 0; s < 2; ++s) {
        const int j = n0 + wn * 32 + s * 16 + ln;
        const float bias = g_bias[mat * DD + j];
        const int h = j >> 5, dd = j & 31;
        #pragma unroll
        for (int m = 0; m < 4; ++m) {
            #pragma unroll
            for (int r = 0; r < 4; ++r) {
                const int rn = r0 + wm * 64 + m * 16 + lg * 4 + r;
                const int b = rn >> 11, n = rn & (NN - 1);
                const int bh = b * HH + h;
                const float val = acc[m][s][r] + bias;
                if (mat == 0) {
                    g_qb[((size_t)bh * NN + n) * HD + dd] = f2b(val * QS);
                } else if (mat == 1) {
                    g_kb[((size_t)bh * NN + n) * HD + dd] = f2b(val);
                } else {
                    g_tA[((size_t)bh * HD + dd) * NN + n] = f2b(val);
                    g_acc[(size_t)rn * DD + j] = g_cf[h * 4] * val;
                }
            }
        }
    }
}

// ---------------------------------------------------------------------------
// Attention pass core (r24-verified body) shared by fused + fallback.
// ---------------------------------------------------------------------------
#define KSP 40    // ks row stride (elems): 32 + 8 pad  (80B, 16B-aligned)
#define TSP 136   // ts row stride (elems): 128 + 8 pad (272B, 16B-aligned)

// ---------------------------------------------------------------------------
// Kernel 2a (r25): FUSED attention — all 3 polynomial passes in one
// cooperative kernel.  Grid 512 x 512thr = exactly co-resident (2 blk/CU;
// LDS 37.9KBx2, 1024 thr, VGPR ~60).  Between passes: __threadfence() +
// grid.sync().  Register-carried state across passes: qf (Q frags), invl
// (pass-1 rowsum), aloc (polynomial accumulator: read g_acc once = c0*V
// term, += ck*val per pass, write g_mg at end — same f32 add order as the
// old RMW chain -> bit-identical; removes ~32MB g_acc/g_invl traffic and
// 2 launch ramps).
// ---------------------------------------------------------------------------
__global__ __launch_bounds__(512, 1) void attn_fused_kernel(int /*dummy*/)
{
    __shared__ unsigned short ks[2][128 * KSP];  // 2 x 10.24 KB
    __shared__ unsigned short ts[2][32 * TSP];   // 2 x 8.7 KB

    cg::grid_group grid = cg::this_grid();

    const int tid = threadIdx.x;
    const int w   = tid >> 6;          // 0..7
    const int l   = tid & 63;
    const int lg  = l >> 4;
    const int ln  = l & 15;

    const int bi = blockIdx.x;                 // grid 512
    const int bh = (bi & 7) * 4 + ((bi >> 3) & 3);   // b*H + h (XCD swizzle)
    const int qt = bi >> 5;                    // 0..15
    const int h  = bh & (HH - 1);
    const int b  = bh >> 3;
    const int q0 = qt * 128;
    const int qw = q0 + w * 16;                // this wave's 16 queries

    const short8 qf = *(const short8*)(g_qb +
        ((size_t)bh * NN + qw + ln) * HD + lg * 8);
    const unsigned short* kb = g_kb + (size_t)bh * NN * HD;

    const int krow = tid >> 2, kcol = (tid & 3) * 8;
    const int trow = tid >> 4, tcol = (tid & 15) * 8;

    const f32x4 zero = {0.f, 0.f, 0.f, 0.f};
    float invl = 0.f;
    f32x4 aloc0 = zero, aloc1 = zero;          // polynomial accumulator
    const size_t rowi = (size_t)(b * NN + qw + ln) * DD + h * HD;

    for (int p = 0; p < 3; ++p) {
        const unsigned short* tb = ((p == 1) ? g_tB : g_tA) + (size_t)bh * HD * NN;
        unsigned short* tout = (p == 1) ? g_tA : g_tB;

        f32x4 o0e = zero, o0o = zero, o1e = zero, o1o = zero;
        float lsum = 0.f;

        // preload it=0
        uint4 krg = *(const uint4*)(kb + tid * 8);
        uint4 trg = *(const uint4*)(tb + (size_t)trow * NN + tcol);
        *(uint4*)(ks[0] + krow * KSP + kcol) = krg;
        *(uint4*)(ts[0] + trow * TSP + tcol) = trg;
        __syncthreads();

        int cur = 0;
        for (int it = 0; it < 16; ++it) {
            if (it < 15) {
                const int k1 = (it + 1) * 128;
                krg = *(const uint4*)(kb + (size_t)k1 * HD + tid * 8);
                trg = *(const uint4*)(tb + (size_t)trow * NN + k1 + tcol);
            }
            const unsigned short* ksc = ks[cur];
            const unsigned short* tsc = ts[cur];

            #pragma unroll
            for (int half = 0; half < 2; ++half) {
                short8 kf[4];
                #pragma unroll
                for (int c = 0; c < 4; ++c)
                    kf[c] = *(const short8*)(ksc + ((half * 4 + c) * 16 + ln) * KSP + lg * 8);
                __builtin_amdgcn_s_setprio(1);
                f32x4 s[4];
                #pragma unroll
                for (int c = 0; c < 4; ++c)
                    s[c] = __builtin_amdgcn_mfma_f32_16x16x32_bf16(kf[c], qf, zero, 0, 0, 0);
                float pp[16];
                #pragma unroll
                for (int c = 0; c < 4; ++c)
                    #pragma unroll
                    for (int r = 0; r < 4; ++r)
                        pp[c * 4 + r] = __builtin_amdgcn_exp2f(s[c][r]);
                if (p == 0) {
                    #pragma unroll
                    for (int e = 0; e < 16; ++e) lsum += pp[e];
                }
                #pragma unroll
                for (int c = 0; c < 4; ++c) {
                    const int cc = half * 4 + c;
                    union { unsigned int u[2]; short4v s4; } pb;
                    pb.u[0] = pk2(pp[c * 4 + 0], pp[c * 4 + 1]);
                    pb.u[1] = pk2(pp[c * 4 + 2], pp[c * 4 + 3]);
                    const short4v tf0 = *(const short4v*)(tsc + ln * TSP + cc * 16 + lg * 4);
                    const short4v tf1 = *(const short4v*)(tsc + (16 + ln) * TSP + cc * 16 + lg * 4);
                    if (cc & 1) {
                        o0o = __builtin_amdgcn_mfma_f32_16x16x16bf16_1k(tf0, pb.s4, o0o, 0, 0, 0);
                        o1o = __builtin_amdgcn_mfma_f32_16x16x16bf16_1k(tf1, pb.s4, o1o, 0, 0, 0);
                    } else {
                        o0e = __builtin_amdgcn_mfma_f32_16x16x16bf16_1k(tf0, pb.s4, o0e, 0, 0, 0);
                        o1e = __builtin_amdgcn_mfma_f32_16x16x16bf16_1k(tf1, pb.s4, o1e, 0, 0, 0);
                    }
                }
                __builtin_amdgcn_s_setprio(0);
            }

            if (it < 15) {
                *(uint4*)(ks[cur ^ 1] + krow * KSP + kcol) = krg;
                *(uint4*)(ts[cur ^ 1] + trow * TSP + tcol) = trg;
            }
            __syncthreads();
            cur ^= 1;
        }

        if (p == 0) {
            lsum += __shfl_xor(lsum, 16, 64);
            lsum += __shfl_xor(lsum, 32, 64);
            invl = 1.0f / lsum;
        }

        const f32x4 oacc0 = o0e + o0o;
        const f32x4 oacc1 = o1e + o1o;
        const float ck = g_cf[h * 4 + p + 1];

        if (p == 0) {   // c0*V term, written by qkv_gemm
            aloc0 = *(const f32x4*)(g_acc + rowi + lg * 4);
            aloc1 = *(const f32x4*)(g_acc + rowi + 16 + lg * 4);
        }
        #pragma unroll
        for (int hf = 0; hf < 2; ++hf) {
            const f32x4& oa = hf ? oacc1 : oacc0;
            f32x4&       al = hf ? aloc1 : aloc0;
            #pragma unroll
            for (int r = 0; r < 4; ++r) {
                const int d = hf * 16 + lg * 4 + r;
                const float val = oa[r] * invl;
                if (p < 2) {
                    tout[((size_t)bh * HD + d) * NN + qw + ln] = f2b(val);
                    al[r] += ck * val;
                } else {
                    g_mg[rowi + d] = f2b(al[r] + ck * val);
                }
            }
        }

        if (p < 2) {
            __threadfence();
            grid.sync();
        }
    }
}

// ---------------------------------------------------------------------------
// Kernel 2b: FALLBACK attention pass (r24 verified, unchanged) — used only
// if cooperative launch is rejected at runtime.
// ---------------------------------------------------------------------------
template<int KIND>
__global__ __launch_bounds__(512, 1) void attn_pass_kernel(const int kidx, const int dir)
{
    __shared__ unsigned short ks[2][128 * KSP];
    __shared__ unsigned short ts[2][32 * TSP];

    const unsigned short* __restrict__ tin  = dir ? g_tB : g_tA;
    unsigned short*       __restrict__ tout = dir ? g_tA : g_tB;

    const int tid = threadIdx.x;
    const int w   = tid >> 6;
    const int l   = tid & 63;
    const int lg  = l >> 4;
    const int ln  = l & 15;

    const int bi = blockIdx.x;
    const int bh = (bi & 7) * 4 + ((bi >> 3) & 3);
    const int qt = bi >> 5;
    const int h  = bh & (HH - 1);
    const int b  = bh >> 3;
    const int q0 = qt * 128;
    const int qw = q0 + w * 16;

    const short8 qf = *(const short8*)(g_qb +
        ((size_t)bh * NN + qw + ln) * HD + lg * 8);

    const unsigned short* kb = g_kb + (size_t)bh * NN * HD;
    const unsigned short* tb = tin  + (size_t)bh * HD * NN;

    const f32x4 zero = {0.f, 0.f, 0.f, 0.f};
    f32x4 o0e = zero, o0o = zero, o1e = zero, o1o = zero;
    float lsum = 0.f;

    const int krow = tid >> 2, kcol = (tid & 3) * 8;
    const int trow = tid >> 4, tcol = (tid & 15) * 8;

    uint4 krg = *(const uint4*)(kb + tid * 8);
    uint4 trg = *(const uint4*)(tb + (size_t)trow * NN + tcol);
    *(uint4*)(ks[0] + krow * KSP + kcol) = krg;
    *(uint4*)(ts[0] + trow * TSP + tcol) = trg;
    __syncthreads();

    int cur = 0;
    for (int it = 0; it < 16; ++it) {
        if (it < 15) {
            const int k1 = (it + 1) * 128;
            krg = *(const uint4*)(kb + (size_t)k1 * HD + tid * 8);
            trg = *(const uint4*)(tb + (size_t)trow * NN + k1 + tcol);
        }
        const unsigned short* ksc = ks[cur];
        const unsigned short* tsc = ts[cur];

        #pragma unroll
        for (int half = 0; half < 2; ++half) {
            short8 kf[4];
            #pragma unroll
            for (int c = 0; c < 4; ++c)
                kf[c] = *(const short8*)(ksc + ((half * 4 + c) * 16 + ln) * KSP + lg * 8);
            __builtin_amdgcn_s_setprio(1);
            f32x4 s[4];
            #pragma unroll
            for (int c = 0; c < 4; ++c)
                s[c] = __builtin_amdgcn_mfma_f32_16x16x32_bf16(kf[c], qf, zero, 0, 0, 0);
            float pp[16];
            #pragma unroll
            for (int c = 0; c < 4; ++c)
                #pragma unroll
                for (int r = 0; r < 4; ++r)
                    pp[c * 4 + r] = __builtin_amdgcn_exp2f(s[c][r]);
            if (KIND == 0) {
                #pragma unroll
                for (int e = 0; e < 16; ++e) lsum += pp[e];
            }
            #pragma unroll
            for (int c = 0; c < 4; ++c) {
                const int cc = half * 4 + c;
                union { unsigned int u[2]; short4v s4; } pb;
                pb.u[0] = pk2(pp[c * 4 + 0], pp[c * 4 + 1]);
                pb.u[1] = pk2(pp[c * 4 + 2], pp[c * 4 + 3]);
                const short4v tf0 = *(const short4v*)(tsc + ln * TSP + cc * 16 + lg * 4);
                const short4v tf1 = *(const short4v*)(tsc + (16 + ln) * TSP + cc * 16 + lg * 4);
                if (cc & 1) {
                    o0o = __builtin_amdgcn_mfma_f32_16x16x16bf16_1k(tf0, pb.s4, o0o, 0, 0, 0);
                    o1o = __builtin_amdgcn_mfma_f32_16x16x16bf16_1k(tf1, pb.s4, o1o, 0, 0, 0);
                } else {
                    o0e = __builtin_amdgcn_mfma_f32_16x16x16bf16_1k(tf0, pb.s4, o0e, 0, 0, 0);
                    o1e = __builtin_amdgcn_mfma_f32_16x16x16bf16_1k(tf1, pb.s4, o1e, 0, 0, 0);
                }
            }
            __builtin_amdgcn_s_setprio(0);
        }

        if (it < 15) {
            *(uint4*)(ks[cur ^ 1] + krow * KSP + kcol) = krg;
            *(uint4*)(ts[cur ^ 1] + trow * TSP + tcol) = trg;
        }
        __syncthreads();
        cur ^= 1;
    }

    const f32x4 oacc0 = o0e + o0o;
    const f32x4 oacc1 = o1e + o1o;

    float invl;
    if (KIND == 0) {
        lsum += __shfl_xor(lsum, 16, 64);
        lsum += __shfl_xor(lsum, 32, 64);
        invl = 1.0f / lsum;
        if (lg == 0) g_invl[(size_t)bh * NN + qw + ln] = invl;
    } else {
        invl = g_invl[(size_t)bh * NN + qw + ln];
    }

    const float ck = g_cf[h * 4 + kidx];
    #pragma unroll
    for (int hf = 0; hf < 2; ++hf) {
        const f32x4& oa = hf ? oacc1 : oacc0;
        #pragma unroll
        for (int r = 0; r < 4; ++r) {
            const int d = hf * 16 + lg * 4 + r;
            const float val = oa[r] * invl;
            const size_t gi = ((size_t)(b * NN + qw + ln)) * DD + h * HD + d;
            if (KIND != 2) {
                tout[((size_t)bh * HD + d) * NN + qw + ln] = f2b(val);
                g_acc[gi] += ck * val;
            } else {
                g_mg[gi] = f2b(g_acc[gi] + ck * val);
            }
        }
    }
}

// ---------------------------------------------------------------------------
// Kernel 3 (r24, kept): output projection GEMM, gll staging.
// ---------------------------------------------------------------------------
__global__ __launch_bounds__(256) void out_gemm_kernel(void* __restrict__ out,
                                                       const void* __restrict__ x)
{
    const int t  = threadIdx.x;
    const int f32m = block_probe(x, t, 256);
    __shared__ unsigned short xs[64 * 32];
    __shared__ unsigned short wl[64 * 32];
    const int w  = t >> 6, l = t & 63, lg = l >> 4, ln = l & 15;
    const int r0 = blockIdx.x * 64;
    const int n0 = blockIdx.y * 64;
    const unsigned short* wt = g_wt + 3 * DD * DD;
    const int sr = t >> 2, sc = (t & 3) * 8;

    f32x4 acc[4] = {{0,0,0,0},{0,0,0,0},{0,0,0,0},{0,0,0,0}};

    for (int kc = 0; kc < DD; kc += 32) {
        __syncthreads();
#if HAS_GLL
        gll16(g_mg + (size_t)(r0 + sr) * DD + kc + sc, xs + sr * 32 + sc);
        gll16(wt   + (size_t)(n0 + sr) * DD + kc + sc, wl + sr * 32 + sc);
#else
        *(uint4*)(xs + sr * 32 + sc) =
            *(const uint4*)(g_mg + (size_t)(r0 + sr) * DD + kc + sc);
        *(uint4*)(wl + sr * 32 + sc) =
            *(const uint4*)(wt + (size_t)(n0 + sr) * DD + kc + sc);
#endif
        __syncthreads();
        const short8 af = *(const short8*)(xs + (w * 16 + ln) * 32 + lg * 8);
        #pragma unroll
        for (int s = 0; s < 4; ++s) {
            const short8 bfr = *(const short8*)(wl + (s * 16 + ln) * 32 + lg * 8);
            acc[s] = __builtin_amdgcn_mfma_f32_16x16x32_bf16(af, bfr, acc[s], 0, 0, 0);
        }
    }

    #pragma unroll
    for (int s = 0; s < 4; ++s) {
        const int j = n0 + s * 16 + ln;
        const float bias = g_bias[3 * DD + j];
        #pragma unroll
        for (int r = 0; r < 4; ++r) {
            const int rn = r0 + w * 16 + lg * 4 + r;
            const float val = acc[s][r] + bias;
            if (f32m) ((float*)out)[(size_t)rn * DD + j] = val;
            else      ((bf16*)out)[(size_t)rn * DD + j] = __float2bfloat16(val);
        }
    }
}

// ---------------------------------------------------------------------------
extern "C" void kernel_launch(void* const* d_in, const int* in_sizes, int n_in,
                              void* d_out, int out_size, void* d_ws, size_t ws_size,
                              hipStream_t stream)
{
    const void* x      = d_in[0];
    const void* Wq     = d_in[1];
    const void* bq     = d_in[2];
    const void* Wk     = d_in[3];
    const void* bk     = d_in[4];
    const void* Wv     = d_in[5];
    const void* bv     = d_in[6];
    const void* Wo     = d_in[7];
    const void* bo     = d_in[8];
    const void* coeffs = d_in[9];
    (void)d_ws; (void)ws_size; (void)in_sizes; (void)n_in; (void)out_size;

    prep_kernel<<<1088, 256, 0, stream>>>(x, Wq, Wk, Wv, Wo,
                                          bq, bk, bv, bo, coeffs);

    qkv_gemm_kernel<<<dim3(64, 4, 3), 256, 0, stream>>>();

    // Fused cooperative attention (512 blocks x 512 thr = exactly
    // co-resident).  If the runtime rejects cooperative launch, nothing was
    // enqueued — fall back to the verified 3-pass path.
    static int s_dummy = 0;
    void* kargs[] = { (void*)&s_dummy };
    hipError_t ce = hipLaunchCooperativeKernel(
        (const void*)attn_fused_kernel, dim3(512), dim3(512), kargs, 0, stream);
    if (ce != hipSuccess) {
        const int agrid = (BB * HH) * (NN / 128);   // 512
        attn_pass_kernel<0><<<agrid, 512, 0, stream>>>(1, 0);
        attn_pass_kernel<1><<<agrid, 512, 0, stream>>>(2, 1);
        attn_pass_kernel<2><<<agrid, 512, 0, stream>>>(3, 0);
    }

    out_gemm_kernel<<<dim3(128, 4), 256, 0, stream>>>(d_out, x);
}

// Round 15
// 209.228 us; speedup vs baseline: 2.6336x; 2.6336x over previous
//
#include <hip/hip_runtime.h>
#include <hip/hip_bf16.h>

typedef __hip_bfloat16 bf16;
typedef __attribute__((ext_vector_type(8))) short short8;   // 8 bf16 = 4 VGPRs
typedef __attribute__((ext_vector_type(4))) short short4v;  // 4 bf16 = 2 VGPRs
typedef __attribute__((ext_vector_type(4))) float f32x4;    // MFMA C/D

#define BB 4
#define NN 2048
#define DD 256
#define HH 8
#define HD 32
#define BN (BB*NN)          // 8192
#define ELEMS (BN*DD)       // 2097152

// ---------------------------------------------------------------------------
// Scratch in module .bss (~33 MB).
// ---------------------------------------------------------------------------
__device__ __attribute__((aligned(256))) unsigned short g_xb [ELEMS]; // x as bf16 [n][k]
__device__ __attribute__((aligned(256))) unsigned short g_qb [ELEMS]; // [bh][n][d] bf16 (pre-scaled)
__device__ __attribute__((aligned(256))) unsigned short g_kb [ELEMS]; // [bh][n][d] bf16
__device__ __attribute__((aligned(256))) unsigned short g_tA [ELEMS]; // [bh][d][n] bf16
__device__ __attribute__((aligned(256))) unsigned short g_tB [ELEMS]; // [bh][d][n] bf16
__device__ __attribute__((aligned(256))) float          g_acc[ELEMS]; // [b][n][D] f32 (c0V+c1T1+c2T2)
__device__ __attribute__((aligned(256))) unsigned short g_mg [ELEMS]; // merged bf16 [n][D] (KIND2 out)
__device__ __attribute__((aligned(256))) unsigned short g_wt [4*DD*DD]; // W^T bf16 [mat][n][k]
__device__ __attribute__((aligned(256))) float g_bias[4*DD];
__device__ __attribute__((aligned(256))) float g_cf[HH*4];
__device__ __attribute__((aligned(256))) float g_invl[BB*HH*NN];      // cached 1/rowsum (pass 1)

__device__ __forceinline__ float b2f(unsigned short u) {
    union { unsigned int i; float f; } c; c.i = ((unsigned int)u) << 16; return c.f;
}
__device__ __forceinline__ unsigned short f2b(float f) {           // safe path
    bf16 h = __float2bfloat16(f);
    return *reinterpret_cast<unsigned short*>(&h);
}
// pack two f32 -> one u32 of two bf16 (RNE).  gfx950 has a 1-instr pk cvt.
#if __has_builtin(__builtin_amdgcn_cvt_pk_bf16_f32)
typedef __attribute__((ext_vector_type(2))) __bf16 bf16x2t;
__device__ __forceinline__ unsigned int pk2(float a, float b) {
    union { bf16x2t v; unsigned int u; } c;
    c.v = __builtin_amdgcn_cvt_pk_bf16_f32(a, b);
    return c.u;
}
#else
__device__ __forceinline__ unsigned int pk2(float a, float b) {
    unsigned int ua = __float_as_uint(a), ub = __float_as_uint(b);
    ua = (ua + 0x7FFFu + ((ua >> 16) & 1u)) >> 16;
    ub = (ub + 0x7FFFu + ((ub >> 16) & 1u)) & 0xFFFF0000u;
    return ua | ub;
}
#endif
__device__ __forceinline__ float ldin(const void* p, int i, int f32m) {
    return f32m ? ((const float*)p)[i] : b2f(((const unsigned short*)p)[i]);
}

// ---------------------------------------------------------------------------
// Async global->LDS (16B/lane).  LDS dest must be wave-uniform-base +
// lane*16 — both gemm staging layouts are linear (slot s <-> LDS byte s*16),
// verified.  Guarded: falls back to uint4 copies if builtin absent.
// ---------------------------------------------------------------------------
#if __has_builtin(__builtin_amdgcn_global_load_lds)
#define HAS_GLL 1
typedef const __attribute__((address_space(1))) unsigned int* gas_t;
typedef __attribute__((address_space(3))) unsigned int* las_t;
__device__ __forceinline__ void gll16(const void* gsrc, void* ldst) {
    __builtin_amdgcn_global_load_lds((gas_t)gsrc, (las_t)ldst, 16, 0, 0);
}
#else
#define HAS_GLL 0
#endif

// ---------------------------------------------------------------------------
// Per-block dtype probe (verified r23).
// ---------------------------------------------------------------------------
__device__ __forceinline__ int block_probe(const void* x, int tid, int nthr)
{
    __shared__ int cnt;
    if (tid == 0) cnt = 0;
    __syncthreads();
    const unsigned short* u = (const unsigned short*)x;
    int w = 0;
    for (int i = tid; i < 1024; i += nthr) {
        const int e = (u[2 * i] >> 7) & 0xFF;
        if (e < 100 || e > 140) ++w;
    }
    if (w) atomicAdd(&cnt, w);
    __syncthreads();
    return cnt > 300;
}

// ---------------------------------------------------------------------------
// Kernel A (r23, kept): merged prep.  Blocks 0..1023: x -> bf16 (g_xb).
// Blocks 1024..1087: W transpose -> g_wt; block 1024 also biases/coeffs.
// ---------------------------------------------------------------------------
__global__ __launch_bounds__(256) void prep_kernel(
    const void* __restrict__ x,
    const void* W0, const void* W1, const void* W2, const void* W3,
    const void* bq, const void* bk, const void* bv, const void* bo,
    const void* coeffs)
{
    const int t = threadIdx.x;
    const int f32m = block_probe(x, t, 256);

    if (blockIdx.x < 1024) {
        const size_t i0 = ((size_t)blockIdx.x * 256 + t) * 8;
        if (f32m) {
            const float4 a = *(const float4*)((const float*)x + i0);
            const float4 b = *(const float4*)((const float*)x + i0 + 4);
            union { uint4 v; unsigned int u[4]; } o;
            o.u[0] = pk2(a.x, a.y); o.u[1] = pk2(a.z, a.w);
            o.u[2] = pk2(b.x, b.y); o.u[3] = pk2(b.z, b.w);
            *(uint4*)(g_xb + i0) = o.v;
        } else {
            *(uint4*)(g_xb + i0) = *(const uint4*)((const unsigned short*)x + i0);
        }
        return;
    }

    __shared__ unsigned short tile[64][65];
    const int bi  = blockIdx.x - 1024;         // 0..63
    const int mat = bi >> 4;
    const int bx  = bi & 15;
    const void* W = (mat == 0) ? W0 : (mat == 1) ? W1 : (mat == 2) ? W2 : W3;
    const int k0 = (bx >> 2) * 64;
    const int n0 = (bx & 3) * 64;

    if (bi == 0) {
        g_bias[0 * DD + t] = ldin(bq, t, f32m);
        g_bias[1 * DD + t] = ldin(bk, t, f32m);
        g_bias[2 * DD + t] = ldin(bv, t, f32m);
        g_bias[3 * DD + t] = ldin(bo, t, f32m);
        if (t < 32) g_cf[t] = ldin(coeffs, t, f32m);
    }

    #pragma unroll
    for (int it = 0; it < 16; ++it) {
        const int flat = it * 256 + t;
        const int i = flat >> 6, j = flat & 63;
        tile[j][i] = f2b(ldin(W, (k0 + i) * DD + n0 + j, f32m));
    }
    __syncthreads();
    unsigned short* wt = g_wt + mat * DD * DD;
    #pragma unroll
    for (int it = 0; it < 16; ++it) {
        const int flat = it * 256 + t;
        const int nl = flat >> 6, kl = flat & 63;
        wt[(n0 + nl) * DD + k0 + kl] = tile[nl][kl];
    }
}

// ---------------------------------------------------------------------------
// Kernel 1 (r24, kept): QKV projection GEMM, 128x64 tile, gll staging.
// ---------------------------------------------------------------------------
__global__ __launch_bounds__(256) void qkv_gemm_kernel()
{
    __shared__ unsigned short xs[128 * 32];   // A tile 8 KB (linear)
    __shared__ unsigned short wl[64 * 32];    // B tile 4 KB (linear)
    const int t  = threadIdx.x;
    const int w  = t >> 6, l = t & 63, lg = l >> 4, ln = l & 15;
    const int wm = w >> 1, wn = w & 1;        // wave -> (M-half, N-half)
    const int r0 = blockIdx.x * 128;
    const int n0 = blockIdx.y * 64;
    const int mat = blockIdx.z;
    const unsigned short* wt = g_wt + mat * DD * DD;

    f32x4 acc[4][2];
    #pragma unroll
    for (int m = 0; m < 4; ++m)
        #pragma unroll
        for (int s = 0; s < 2; ++s) acc[m][s] = (f32x4){0,0,0,0};

    for (int kc = 0; kc < DD; kc += 32) {
        __syncthreads();
#if HAS_GLL
        #pragma unroll
        for (int c = 0; c < 2; ++c) {
            const int s = c * 256 + t;
            gll16(g_xb + (size_t)(r0 + (s >> 2)) * DD + kc + (s & 3) * 8,
                  xs + (s >> 2) * 32 + (s & 3) * 8);
        }
        gll16(wt + (size_t)(n0 + (t >> 2)) * DD + kc + (t & 3) * 8,
              wl + (t >> 2) * 32 + (t & 3) * 8);
#else
        #pragma unroll
        for (int c = 0; c < 2; ++c) {
            const int s = c * 256 + t;
            *(uint4*)(xs + (s >> 2) * 32 + (s & 3) * 8) =
                *(const uint4*)(g_xb + (size_t)(r0 + (s >> 2)) * DD + kc + (s & 3) * 8);
        }
        *(uint4*)(wl + (t >> 2) * 32 + (t & 3) * 8) =
            *(const uint4*)(wt + (size_t)(n0 + (t >> 2)) * DD + kc + (t & 3) * 8);
#endif
        __syncthreads();

        short8 af[4];
        #pragma unroll
        for (int m = 0; m < 4; ++m)
            af[m] = *(const short8*)(xs + (wm * 64 + m * 16 + ln) * 32 + lg * 8);
        #pragma unroll
        for (int s = 0; s < 2; ++s) {
            const short8 bfr = *(const short8*)(wl + (wn * 32 + s * 16 + ln) * 32 + lg * 8);
            #pragma unroll
            for (int m = 0; m < 4; ++m)
                acc[m][s] = __builtin_amdgcn_mfma_f32_16x16x32_bf16(af[m], bfr, acc[m][s], 0, 0, 0);
        }
    }

    const float QS = 0.17677669529663687f * 1.4426950408889634f; // scale*log2e
    #pragma unroll
    for (int s = 0; s < 2; ++s) {
        const int j = n0 + wn * 32 + s * 16 + ln;
        const float bias = g_bias[mat * DD + j];
        const int h = j >> 5, dd = j & 31;
        #pragma unroll
        for (int m = 0; m < 4; ++m) {
            #pragma unroll
            for (int r = 0; r < 4; ++r) {
                const int rn = r0 + wm * 64 + m * 16 + lg * 4 + r;
                const int b = rn >> 11, n = rn & (NN - 1);
                const int bh = b * HH + h;
                const float val = acc[m][s][r] + bias;
                if (mat == 0) {
                    g_qb[((size_t)bh * NN + n) * HD + dd] = f2b(val * QS);
                } else if (mat == 1) {
                    g_kb[((size_t)bh * NN + n) * HD + dd] = f2b(val);
                } else {
                    g_tA[((size_t)bh * HD + dd) * NN + n] = f2b(val);
                    g_acc[(size_t)rn * DD + j] = g_cf[h * 4] * val;
                }
            }
        }
    }
}

// ---------------------------------------------------------------------------
// Kernel 2 (r24, restored verbatim): attention pass — query-split waves,
// dbuf LDS (1 barrier/it, issue-early/write-late), phase-split c-loop,
// s_setprio around the compute cluster.  Verified 44.7us/pass, total 209.5.
// r25 post-mortem: cooperative grid.sync fusion = 436us (~150us/sync on
// MI355X) — separate launches ARE the cheap global barrier here.  Reverted.
//  KIND=0: lsum, caches 1/rowsum.  KIND=1: loads cached invl.
//  KIND=2: merges into g_mg bf16 (no tout).
// ---------------------------------------------------------------------------
#define KSP 40    // ks row stride (elems): 32 + 8 pad  (80B, 16B-aligned)
#define TSP 136   // ts row stride (elems): 128 + 8 pad (272B, 16B-aligned)
template<int KIND>
__global__ __launch_bounds__(512, 1) void attn_pass_kernel(const int kidx, const int dir)
{
    __shared__ unsigned short ks[2][128 * KSP];  // 2 x 10.24 KB
    __shared__ unsigned short ts[2][32 * TSP];   // 2 x 8.7 KB

    const unsigned short* __restrict__ tin  = dir ? g_tB : g_tA;
    unsigned short*       __restrict__ tout = dir ? g_tA : g_tB;

    const int tid = threadIdx.x;
    const int w   = tid >> 6;          // 0..7
    const int l   = tid & 63;
    const int lg  = l >> 4;
    const int ln  = l & 15;

    // XCD swizzle (verified r15): all 16 q-tiles of a bh on one XCD.
    const int bi = blockIdx.x;                 // grid 512
    const int bh = (bi & 7) * 4 + ((bi >> 3) & 3);   // b*H + h
    const int qt = bi >> 5;                    // 0..15
    const int h  = bh & (HH - 1);
    const int b  = bh >> 3;
    const int q0 = qt * 128;
    const int qw = q0 + w * 16;                // this wave's 16 queries

    const short8 qf = *(const short8*)(g_qb +
        ((size_t)bh * NN + qw + ln) * HD + lg * 8);

    const unsigned short* kb = g_kb + (size_t)bh * NN * HD;
    const unsigned short* tb = tin  + (size_t)bh * HD * NN;

    const f32x4 zero = {0.f, 0.f, 0.f, 0.f};
    f32x4 o0e = zero, o0o = zero, o1e = zero, o1o = zero;  // 4 PV chains
    float lsum = 0.f;

    // staging indices (512 threads: 1 ks slot + 1 ts slot each)
    const int krow = tid >> 2, kcol = (tid & 3) * 8;
    const int trow = tid >> 4, tcol = (tid & 15) * 8;

    // preload it=0
    uint4 krg = *(const uint4*)(kb + tid * 8);
    uint4 trg = *(const uint4*)(tb + (size_t)trow * NN + tcol);
    *(uint4*)(ks[0] + krow * KSP + kcol) = krg;
    *(uint4*)(ts[0] + trow * TSP + tcol) = trg;
    __syncthreads();

    int cur = 0;
    for (int it = 0; it < 16; ++it) {
        // issue-early: global loads for it+1 (latency hides under compute)
        if (it < 15) {
            const int k1 = (it + 1) * 128;
            krg = *(const uint4*)(kb + (size_t)k1 * HD + tid * 8);
            trg = *(const uint4*)(tb + (size_t)trow * NN + k1 + tcol);
        }
        const unsigned short* ksc = ks[cur];
        const unsigned short* tsc = ts[cur];

        #pragma unroll
        for (int half = 0; half < 2; ++half) {
            short8 kf[4];
            #pragma unroll
            for (int c = 0; c < 4; ++c)
                kf[c] = *(const short8*)(ksc + ((half * 4 + c) * 16 + ln) * KSP + lg * 8);
            __builtin_amdgcn_s_setprio(1);
            f32x4 s[4];
            #pragma unroll
            for (int c = 0; c < 4; ++c)
                s[c] = __builtin_amdgcn_mfma_f32_16x16x32_bf16(kf[c], qf, zero, 0, 0, 0);
            float p[16];
            #pragma unroll
            for (int c = 0; c < 4; ++c)
                #pragma unroll
                for (int r = 0; r < 4; ++r)
                    p[c * 4 + r] = __builtin_amdgcn_exp2f(s[c][r]);
            if (KIND == 0) {
                #pragma unroll
                for (int e = 0; e < 16; ++e) lsum += p[e];
            }
            #pragma unroll
            for (int c = 0; c < 4; ++c) {
                const int cc = half * 4 + c;
                union { unsigned int u[2]; short4v s4; } pb;
                pb.u[0] = pk2(p[c * 4 + 0], p[c * 4 + 1]);
                pb.u[1] = pk2(p[c * 4 + 2], p[c * 4 + 3]);
                const short4v tf0 = *(const short4v*)(tsc + ln * TSP + cc * 16 + lg * 4);
                const short4v tf1 = *(const short4v*)(tsc + (16 + ln) * TSP + cc * 16 + lg * 4);
                if (cc & 1) {
                    o0o = __builtin_amdgcn_mfma_f32_16x16x16bf16_1k(tf0, pb.s4, o0o, 0, 0, 0);
                    o1o = __builtin_amdgcn_mfma_f32_16x16x16bf16_1k(tf1, pb.s4, o1o, 0, 0, 0);
                } else {
                    o0e = __builtin_amdgcn_mfma_f32_16x16x16bf16_1k(tf0, pb.s4, o0e, 0, 0, 0);
                    o1e = __builtin_amdgcn_mfma_f32_16x16x16bf16_1k(tf1, pb.s4, o1e, 0, 0, 0);
                }
            }
            __builtin_amdgcn_s_setprio(0);
        }

        // write-late: stage it+1 into the other buffer, then single barrier
        if (it < 15) {
            *(uint4*)(ks[cur ^ 1] + krow * KSP + kcol) = krg;
            *(uint4*)(ts[cur ^ 1] + trow * TSP + tcol) = trg;
        }
        __syncthreads();
        cur ^= 1;
    }

    const f32x4 oacc0 = o0e + o0o;
    const f32x4 oacc1 = o1e + o1o;

    // rowsum: wave covers ALL keys -> reduce across lg groups only.
    float invl;
    if (KIND == 0) {
        lsum += __shfl_xor(lsum, 16, 64);
        lsum += __shfl_xor(lsum, 32, 64);
        invl = 1.0f / lsum;
        if (lg == 0) g_invl[(size_t)bh * NN + qw + ln] = invl;
    } else {
        invl = g_invl[(size_t)bh * NN + qw + ln];
    }

    // in-register epilogue: lane holds C[d = hf*16+lg*4+r][q = ln].
    const float ck = g_cf[h * 4 + kidx];
    #pragma unroll
    for (int hf = 0; hf < 2; ++hf) {
        const f32x4& oa = hf ? oacc1 : oacc0;
        #pragma unroll
        for (int r = 0; r < 4; ++r) {
            const int d = hf * 16 + lg * 4 + r;
            const float val = oa[r] * invl;
            const size_t gi = ((size_t)(b * NN + qw + ln)) * DD + h * HD + d;
            if (KIND != 2) {
                tout[((size_t)bh * HD + d) * NN + qw + ln] = f2b(val);
                g_acc[gi] += ck * val;
            } else {
                g_mg[gi] = f2b(g_acc[gi] + ck * val);   // final merged, bf16
            }
        }
    }
}

// ---------------------------------------------------------------------------
// Kernel 3 (r24, kept): output projection GEMM, gll staging.
// ---------------------------------------------------------------------------
__global__ __launch_bounds__(256) void out_gemm_kernel(void* __restrict__ out,
                                                       const void* __restrict__ x)
{
    const int t  = threadIdx.x;
    const int f32m = block_probe(x, t, 256);
    __shared__ unsigned short xs[64 * 32];
    __shared__ unsigned short wl[64 * 32];
    const int w  = t >> 6, l = t & 63, lg = l >> 4, ln = l & 15;
    const int r0 = blockIdx.x * 64;
    const int n0 = blockIdx.y * 64;
    const unsigned short* wt = g_wt + 3 * DD * DD;
    const int sr = t >> 2, sc = (t & 3) * 8;

    f32x4 acc[4] = {{0,0,0,0},{0,0,0,0},{0,0,0,0},{0,0,0,0}};

    for (int kc = 0; kc < DD; kc += 32) {
        __syncthreads();
#if HAS_GLL
        gll16(g_mg + (size_t)(r0 + sr) * DD + kc + sc, xs + sr * 32 + sc);
        gll16(wt   + (size_t)(n0 + sr) * DD + kc + sc, wl + sr * 32 + sc);
#else
        *(uint4*)(xs + sr * 32 + sc) =
            *(const uint4*)(g_mg + (size_t)(r0 + sr) * DD + kc + sc);
        *(uint4*)(wl + sr * 32 + sc) =
            *(const uint4*)(wt + (size_t)(n0 + sr) * DD + kc + sc);
#endif
        __syncthreads();
        const short8 af = *(const short8*)(xs + (w * 16 + ln) * 32 + lg * 8);
        #pragma unroll
        for (int s = 0; s < 4; ++s) {
            const short8 bfr = *(const short8*)(wl + (s * 16 + ln) * 32 + lg * 8);
            acc[s] = __builtin_amdgcn_mfma_f32_16x16x32_bf16(af, bfr, acc[s], 0, 0, 0);
        }
    }

    #pragma unroll
    for (int s = 0; s < 4; ++s) {
        const int j = n0 + s * 16 + ln;
        const float bias = g_bias[3 * DD + j];
        #pragma unroll
        for (int r = 0; r < 4; ++r) {
            const int rn = r0 + w * 16 + lg * 4 + r;
            const float val = acc[s][r] + bias;
            if (f32m) ((float*)out)[(size_t)rn * DD + j] = val;
            else      ((bf16*)out)[(size_t)rn * DD + j] = __float2bfloat16(val);
        }
    }
}

// ---------------------------------------------------------------------------
extern "C" void kernel_launch(void* const* d_in, const int* in_sizes, int n_in,
                              void* d_out, int out_size, void* d_ws, size_t ws_size,
                              hipStream_t stream)
{
    const void* x      = d_in[0];
    const void* Wq     = d_in[1];
    const void* bq     = d_in[2];
    const void* Wk     = d_in[3];
    const void* bk     = d_in[4];
    const void* Wv     = d_in[5];
    const void* bv     = d_in[6];
    const void* Wo     = d_in[7];
    const void* bo     = d_in[8];
    const void* coeffs = d_in[9];
    (void)d_ws; (void)ws_size; (void)in_sizes; (void)n_in; (void)out_size;

    prep_kernel<<<1088, 256, 0, stream>>>(x, Wq, Wk, Wv, Wo,
                                          bq, bk, bv, bo, coeffs);

    qkv_gemm_kernel<<<dim3(64, 4, 3), 256, 0, stream>>>();

    const int agrid = (BB * HH) * (NN / 128);   // 32 * 16 = 512 blocks
    attn_pass_kernel<0><<<agrid, 512, 0, stream>>>(1, 0); // tA -> tB, caches invl
    attn_pass_kernel<1><<<agrid, 512, 0, stream>>>(2, 1); // tB -> tA, uses invl
    attn_pass_kernel<2><<<agrid, 512, 0, stream>>>(3, 0); // tA -> g_mg (merged)

    out_gemm_kernel<<<dim3(128, 4), 256, 0, stream>>>(d_out, x);
}